// Round 2
// baseline (12.089 us; speedup 1.0000x reference)
//
#include <hip/hip_runtime.h>
#include <math.h>

// Math: per qubit i, theta = w[i] + (i<2 ? x[i] : 0), phi = theta/2.
//   state_i = [cos(phi), -i*sin(phi)]^T   (complex64, shape (n,2,1))
//   O_i     = cos(theta)                  (complex64 real, shape (n,1,1))
//
// Harness stores complex64 outputs as float32 real parts (out_size = 3n):
//   out[2i+0] = cos(phi)   (Re s0)
//   out[2i+1] = 0          (Re s1 = Re(-i sin) = 0)
//   out[2n+i] = cos(theta) (Re O)
// Fallback (out_size = 6n): full complex interleaved [re,im] pairs:
//   out[4i..4i+3] = {cos(phi), 0, 0, -sin(phi)};  out[4n+2i..] = {cos(theta), 0}

__global__ __launch_bounds__(256) void qubit_rx_real(
    const float* __restrict__ x,
    const float* __restrict__ w,
    float* __restrict__ out,
    int n)  // even
{
    const int npairs = n >> 1;
    int pair = blockIdx.x * blockDim.x + threadIdx.x;
    if (pair >= npairs) return;

    const int i0 = pair * 2;
    float2 wv = *reinterpret_cast<const float2*>(w + i0);

    float t0 = wv.x, t1 = wv.y;
    if (i0 == 0) { t0 += x[0]; t1 += x[1]; }  // only qubits 0,1 get data angles

    float s0, c0, s1, c1;
    sincosf(0.5f * t0, &s0, &c0);
    sincosf(0.5f * t1, &s1, &c1);

    // state block: 2 floats per qubit -> float4 per pair
    reinterpret_cast<float4*>(out)[pair] = make_float4(c0, 0.0f, c1, 0.0f);
    // O block at out + 2n: 1 float per qubit -> float2 per pair
    reinterpret_cast<float2*>(out + (size_t)2 * n)[pair] =
        make_float2(c0 * c0 - s0 * s0, c1 * c1 - s1 * s1);
}

__global__ __launch_bounds__(256) void qubit_rx_cplx(
    const float* __restrict__ x,
    const float* __restrict__ w,
    float* __restrict__ out,
    int n)
{
    const int npairs = n >> 1;
    int pair = blockIdx.x * blockDim.x + threadIdx.x;
    if (pair >= npairs) return;

    const int i0 = pair * 2;
    float2 wv = *reinterpret_cast<const float2*>(w + i0);

    float t0 = wv.x, t1 = wv.y;
    if (i0 == 0) { t0 += x[0]; t1 += x[1]; }

    float s0, c0, s1, c1;
    sincosf(0.5f * t0, &s0, &c0);
    sincosf(0.5f * t1, &s1, &c1);

    reinterpret_cast<float4*>(out)[i0]     = make_float4(c0, 0.0f, 0.0f, -s0);
    reinterpret_cast<float4*>(out)[i0 + 1] = make_float4(c1, 0.0f, 0.0f, -s1);
    reinterpret_cast<float4*>(out + (size_t)4 * n)[pair] =
        make_float4(c0 * c0 - s0 * s0, 0.0f, c1 * c1 - s1 * s1, 0.0f);
}

extern "C" void kernel_launch(void* const* d_in, const int* in_sizes, int n_in,
                              void* d_out, int out_size, void* d_ws, size_t ws_size,
                              hipStream_t stream) {
    const float* x = (const float*)d_in[0];   // (2,)
    const float* w = (const float*)d_in[1];   // (N_QUBITS,)
    float* out = (float*)d_out;
    const int n = in_sizes[1];                // 2,000,000

    const int npairs = n >> 1;
    const int block = 256;
    const int grid = (npairs + block - 1) / block;

    if (out_size >= 6 * (long long)n) {
        // full complex interleaved layout (48 MB)
        qubit_rx_cplx<<<grid, block, 0, stream>>>(x, w, out, n);
    } else {
        // real-part-only layout (24 MB): out_size == 3n
        qubit_rx_real<<<grid, block, 0, stream>>>(x, w, out, n);
    }
}

// Round 3
// 11.596 us; speedup vs baseline: 1.0425x; 1.0425x over previous
//
#include <hip/hip_runtime.h>
#include <math.h>

// Math: per qubit i, theta = w[i] + (i<2 ? x[i] : 0), phi = theta/2.
//   state_i = [cos(phi), -i*sin(phi)]^T   (complex64, (n,2,1))
//   O_i     = cos(theta) = cos^2(phi) - sin^2(phi)   (real)
//
// Harness stores complex64 outputs as float32 REAL PARTS (out_size = 3n):
//   out[2i+0] = cos(phi)    (Re s0)
//   out[2i+1] = 0           (Re s1 = Re(-i sin) = 0)
//   out[2n+i] = cos(theta)  (Re O)
//
// 4 qubits per thread: 1x float4 load (w), 2x float4 state stores,
// 1x float4 O store — every stream 16 B/lane, fully coalesced.
// __sinf/__cosf: HW v_sin_f32/v_cos_f32 (mul by inline-const 1/2pi + trans op),
// ~1e-6 abs error on |phi|<~3 — far below the 2e-2 threshold.

__global__ __launch_bounds__(256) void qubit_rx4(
    const float* __restrict__ x,
    const float* __restrict__ w,
    float* __restrict__ out,
    int n)  // n % 4 == 0
{
    const int nquads = n >> 2;
    int quad = blockIdx.x * blockDim.x + threadIdx.x;
    if (quad >= nquads) return;

    float4 wv = reinterpret_cast<const float4*>(w)[quad];
    float t0 = wv.x, t1 = wv.y, t2 = wv.z, t3 = wv.w;
    if (quad == 0) { t0 += x[0]; t1 += x[1]; }  // data-encoding on qubits 0,1 only

    float p0 = 0.5f * t0, p1 = 0.5f * t1, p2 = 0.5f * t2, p3 = 0.5f * t3;
    float c0 = __cosf(p0), s0 = __sinf(p0);
    float c1 = __cosf(p1), s1 = __sinf(p1);
    float c2 = __cosf(p2), s2 = __sinf(p2);
    float c3 = __cosf(p3), s3 = __sinf(p3);

    // state block: 2 floats/qubit -> 2 float4 per quad
    float4* st = reinterpret_cast<float4*>(out);
    st[quad * 2 + 0] = make_float4(c0, 0.0f, c1, 0.0f);
    st[quad * 2 + 1] = make_float4(c2, 0.0f, c3, 0.0f);

    // O block at out + 2n: 1 float/qubit -> 1 float4 per quad
    reinterpret_cast<float4*>(out + (size_t)2 * n)[quad] =
        make_float4(c0 * c0 - s0 * s0,
                    c1 * c1 - s1 * s1,
                    c2 * c2 - s2 * s2,
                    c3 * c3 - s3 * s3);
}

extern "C" void kernel_launch(void* const* d_in, const int* in_sizes, int n_in,
                              void* d_out, int out_size, void* d_ws, size_t ws_size,
                              hipStream_t stream) {
    const float* x = (const float*)d_in[0];   // (2,)
    const float* w = (const float*)d_in[1];   // (N_QUBITS,)
    float* out = (float*)d_out;               // 3n floats (real parts of complex64)
    const int n = in_sizes[1];                // 2,000,000

    const int nquads = n >> 2;
    const int block = 256;
    const int grid = (nquads + block - 1) / block;
    qubit_rx4<<<grid, block, 0, stream>>>(x, w, out, n);
}

// Round 5
// 11.435 us; speedup vs baseline: 1.0571x; 1.0141x over previous
//
#include <hip/hip_runtime.h>
#include <math.h>

// Math: per qubit i, theta = w[i] + (i<2 ? x[i] : 0), phi = theta/2.
//   state_i = [cos(phi), -i*sin(phi)]^T   (complex64, (n,2,1))
//   O_i     = cos(theta) = cos^2(phi) - sin^2(phi)   (real)
//
// Harness stores complex64 outputs as float32 REAL PARTS (out_size = 3n):
//   out[2i+0] = cos(phi)    (Re s0)
//   out[2i+1] = 0           (Re s1 = Re(-i sin) = 0)
//   out[2n+i] = cos(theta)  (Re O)
//
// Pure streaming kernel: 8 MB read, 24 MB write, zero reuse.
// -> nontemporal loads/stores (`nt`) to skip cache allocation; the 24 MB
//    write stream otherwise churns the 32 MB aggregate L2.
// Note: __builtin_nontemporal_* requires native clang vectors, not
// HIP_vector_type structs -> use ext_vector_type(4) float.

typedef float f4 __attribute__((ext_vector_type(4)));

__global__ __launch_bounds__(1024) void qubit_rx4_nt(
    const float* __restrict__ x,
    const float* __restrict__ w,
    float* __restrict__ out,
    int n)  // n % 4 == 0
{
    const int nquads = n >> 2;
    int quad = blockIdx.x * blockDim.x + threadIdx.x;
    if (quad >= nquads) return;

    f4 wv = __builtin_nontemporal_load(reinterpret_cast<const f4*>(w) + quad);
    float t0 = wv.x, t1 = wv.y, t2 = wv.z, t3 = wv.w;
    if (quad == 0) { t0 += x[0]; t1 += x[1]; }  // data-encoding on qubits 0,1 only

    float p0 = 0.5f * t0, p1 = 0.5f * t1, p2 = 0.5f * t2, p3 = 0.5f * t3;
    float c0 = __cosf(p0), s0 = __sinf(p0);
    float c1 = __cosf(p1), s1 = __sinf(p1);
    float c2 = __cosf(p2), s2 = __sinf(p2);
    float c3 = __cosf(p3), s3 = __sinf(p3);

    // state block: 2 floats/qubit -> 2 f4 per quad
    f4* st = reinterpret_cast<f4*>(out);
    f4 s_lo = {c0, 0.0f, c1, 0.0f};
    f4 s_hi = {c2, 0.0f, c3, 0.0f};
    __builtin_nontemporal_store(s_lo, st + quad * 2 + 0);
    __builtin_nontemporal_store(s_hi, st + quad * 2 + 1);

    // O block at out + 2n: 1 float/qubit -> 1 f4 per quad
    f4 ov = {c0 * c0 - s0 * s0,
             c1 * c1 - s1 * s1,
             c2 * c2 - s2 * s2,
             c3 * c3 - s3 * s3};
    __builtin_nontemporal_store(ov, reinterpret_cast<f4*>(out + (size_t)2 * n) + quad);
}

extern "C" void kernel_launch(void* const* d_in, const int* in_sizes, int n_in,
                              void* d_out, int out_size, void* d_ws, size_t ws_size,
                              hipStream_t stream) {
    const float* x = (const float*)d_in[0];   // (2,)
    const float* w = (const float*)d_in[1];   // (N_QUBITS,)
    float* out = (float*)d_out;               // 3n floats (real parts of complex64)
    const int n = in_sizes[1];                // 2,000,000

    const int nquads = n >> 2;                // 500,000
    const int block = 1024;
    const int grid = (nquads + block - 1) / block;  // 489
    qubit_rx4_nt<<<grid, block, 0, stream>>>(x, w, out, n);
}